// Round 9
// baseline (290.935 us; speedup 1.0000x reference)
//
#include <hip/hip_runtime.h>

#define NB_CONV 256
#define NB_TOTAL 1792          // 7 blocks/CU exactly (LDS 22,020 B -> 7/CU); all resident at t=0
#define NTHR 256
#define CHUNK_F4 1024          // 16 KB contiguous chunk per steal
#define NCHUNK 16384           // 16,777,216 f4 / 1024
#define TOTAL_F4 (4096 * 4096)

typedef float f4 __attribute__((ext_vector_type(4)));

// d_out layout: y[4096][64] followed by cache_new[4096][4][64][64]
// R8-proven base (103.6 us) + work-stealing copy: every wave (conv blocks too,
// after their conv) steals 16 KB contiguous chunks until done. Perfect balance,
// zero idle slots, page-local 4-deep MLP per thread. Plain loads (keep L3 read
// hits) + NT stores (don't pollute L3 with the write stream).
__global__ __launch_bounds__(256)
void fmc_fused(const float* __restrict__ inputs,
               const float* __restrict__ cache,
               const float* __restrict__ wk,
               const float* __restrict__ bias,
               const int* __restrict__ idxp,
               float* __restrict__ y_out,
               float* __restrict__ cache_out,
               unsigned int* __restrict__ ctr)
{
    const int idx = idxp[0];
    int iw = idx % 64;        if (iw < 0)  iw += 64;
    int iwi = (idx - 1) % 64; if (iwi < 0) iwi += 64;
    const bool upd = (idx - 1) >= 0;   // EXCLUSIVE=True
    const int tid = threadIdx.x;

    if (blockIdx.x < NB_CONV) {
        // ---------------- conv part: y[b][fo] for 16 batch rows ----------------
        __shared__ float Ws[64][68];   // [ci][fo], padded -> conflict-free
        __shared__ float Xs[64][18];   // [ci][b],  padded -> conflict-free
        const int bbase = blockIdx.x * 16;
        const int fog = tid & 15;      // fo group: fo = 4*fog
        const int bp  = tid >> 4;      // compute threads: bp<8 -> b pair

        float acc[2][4];
        if (tid < 128) {
            const f4 bv = *(const f4*)(bias + (fog << 2));
            acc[0][0]=bv.x; acc[0][1]=bv.y; acc[0][2]=bv.z; acc[0][3]=bv.w;
            acc[1][0]=bv.x; acc[1][1]=bv.y; acc[1][2]=bv.z; acc[1][3]=bv.w;
        }

        for (int kh = 0; kh < 4; ++kh) {
            for (int kw = 0; kw < 7; ++kw) {
                if (kh == 3 && kw >= 3) break;          // autoregressive mask
                const int col = iw - 3 + kw;            // window col -> cache col
                int kind;                                // 0 zero, 1 inputs, 2 cache
                int hs = kh;
                if (col < 0 || col >= 64) kind = 0;
                else if (!upd) kind = 2;
                else if (iw != 0) kind = (kh == 3 && col == iwi) ? 1 : 2;   // case A
                else if (iwi != 0) {                                        // case B: shift(add)
                    if (kh == 3) kind = 0;
                    else if (kh == 2 && col == iwi) kind = 1;
                    else { kind = 2; hs = kh + 1; }
                } else {                                                     // case C: add(shift)
                    if (kh == 3) kind = (col == 0) ? 1 : 0;
                    else { kind = 2; hs = kh + 1; }
                }

                __syncthreads();   // protect LDS from previous tap's readers
                // stage W tap: [ci][fo] 64x64
                const float* wt = wk + (kh * 7 + kw) * 4096;
                #pragma unroll
                for (int i = 0; i < 4; ++i) {
                    const int f4i = tid + (i << 8);
                    const int ci = f4i >> 4;
                    const int fo = (f4i & 15) << 2;
                    *(f4*)&Ws[ci][fo] = *(const f4*)(wt + ci * 64 + fo);
                }
                // stage X (transposed): Xs[ci][b]
                {
                    const int bl = tid >> 4;
                    const int c4i = (tid & 15) << 2;
                    f4 v = (f4)(0.f);
                    if (kind == 1)
                        v = *(const f4*)(inputs + (bbase + bl) * 64 + c4i);
                    else if (kind == 2)
                        v = *(const f4*)(cache + ((((bbase + bl) << 2) + hs) * 64 + col) * 64 + c4i);
                    Xs[c4i + 0][bl] = v.x;
                    Xs[c4i + 1][bl] = v.y;
                    Xs[c4i + 2][bl] = v.z;
                    Xs[c4i + 3][bl] = v.w;
                }
                __syncthreads();

                if (tid < 128) {
                    #pragma unroll 16
                    for (int ci = 0; ci < 64; ++ci) {
                        const f4 w = *(const f4*)&Ws[ci][fog << 2];
                        const float2 x = *(const float2*)&Xs[ci][bp << 1];
                        acc[0][0] = fmaf(x.x, w.x, acc[0][0]);
                        acc[0][1] = fmaf(x.x, w.y, acc[0][1]);
                        acc[0][2] = fmaf(x.x, w.z, acc[0][2]);
                        acc[0][3] = fmaf(x.x, w.w, acc[0][3]);
                        acc[1][0] = fmaf(x.y, w.x, acc[1][0]);
                        acc[1][1] = fmaf(x.y, w.y, acc[1][1]);
                        acc[1][2] = fmaf(x.y, w.z, acc[1][2]);
                        acc[1][3] = fmaf(x.y, w.w, acc[1][3]);
                    }
                }
            }
        }
        if (tid < 128) {
            float* y0 = y_out + (bbase + (bp << 1)) * 64 + (fog << 2);
            *(f4*)y0        = (f4){acc[0][0], acc[0][1], acc[0][2], acc[0][3]};
            *(f4*)(y0 + 64) = (f4){acc[1][0], acc[1][1], acc[1][2], acc[1][3]};
        }
        // fall through: conv blocks join the copy pool
    }

    // ---------------- copy part: per-wave work-stealing over 16 KB chunks ----
    {
        const f4* __restrict__ c4 = (const f4*)cache;
        const f4* __restrict__ i4 = (const f4*)inputs;
        f4* __restrict__ o4 = (f4*)cache_out;
        const int lane = tid & 63;
        // f4-index residue layout within a batch row: h[2] w[6] e[4] (4096 f4/row)
        const int caseid = !upd ? 0 : (iw != 0 ? 1 : (iwi != 0 ? 2 : 3));
        const int targetA = 3072 + (iwi << 4);   // h==3, w==iwi

        while (true) {
            int c;
            if (lane == 0) c = (int)atomicAdd(ctr, 1u);
            c = __shfl(c, 0);
            if (c >= NCHUNK) break;
            const int base = c << 10;            // chunk = 1024 consecutive f4

            if (caseid == 0) {                   // idx==0: plain copy
                #pragma unroll 4
                for (int it = 0; it < CHUNK_F4 / 64; ++it) {
                    const int i = base + (it << 6) + lane;
                    __builtin_nontemporal_store(c4[i], o4 + i);
                }
            } else if (caseid == 1) {            // case A: copy + column override
                #pragma unroll 4
                for (int it = 0; it < CHUNK_F4 / 64; ++it) {
                    const int i = base + (it << 6) + lane;
                    const int r = i & 4095;
                    const f4* src = ((r & 4080) == targetA)
                                    ? (i4 + ((i >> 12) << 4) + (r & 15))
                                    : (c4 + i);
                    __builtin_nontemporal_store(*src, o4 + i);
                }
            } else if (caseid == 2) {            // case B: row shift, insert at (2,iwi), zero row 3
                for (int it = 0; it < CHUNK_F4 / 64; ++it) {
                    const int i = base + (it << 6) + lane;
                    const int r = i & 4095;
                    const int h = r >> 10, w = (r >> 4) & 63;
                    f4 v = (f4)(0.f);
                    if (h == 2 && w == iwi) v = i4[((i >> 12) << 4) + (r & 15)];
                    else if (h < 3) v = c4[i + 1024];
                    __builtin_nontemporal_store(v, o4 + i);
                }
            } else {                             // case C: row shift, row 3 = inputs at col 0 else 0
                for (int it = 0; it < CHUNK_F4 / 64; ++it) {
                    const int i = base + (it << 6) + lane;
                    const int r = i & 4095;
                    const int h = r >> 10, w = (r >> 4) & 63;
                    f4 v = (f4)(0.f);
                    if (h == 3) { if (w == 0) v = i4[((i >> 12) << 4) + (r & 15)]; }
                    else v = c4[i + 1024];
                    __builtin_nontemporal_store(v, o4 + i);
                }
            }
        }
    }
}

extern "C" void kernel_launch(void* const* d_in, const int* in_sizes, int n_in,
                              void* d_out, int out_size, void* d_ws, size_t ws_size,
                              hipStream_t stream) {
    const float* inputs = (const float*)d_in[0];
    const float* cache  = (const float*)d_in[1];
    const float* wk     = (const float*)d_in[2];
    const float* bias   = (const float*)d_in[3];
    const int*   idxp   = (const int*)d_in[4];
    float* y_out = (float*)d_out;
    float* cache_out = (float*)d_out + 4096 * 64;
    unsigned int* ctr = (unsigned int*)d_ws;

    hipMemsetAsync(ctr, 0, sizeof(unsigned int), stream);   // capture-legal graph node
    fmc_fused<<<NB_TOTAL, NTHR, 0, stream>>>(inputs, cache, wk, bias, idxp,
                                             y_out, cache_out, ctr);
}

// Round 10
// 109.961 us; speedup vs baseline: 2.6458x; 2.6458x over previous
//
#include <hip/hip_runtime.h>

#define NB_CONV 256
#define NB_COPYF 1536            // full-share copy blocks
#define NB_TOTAL (NB_CONV + NB_COPYF)   // 1792 = 7 blocks/CU, all resident at t=0
#define NTHR 256
#define NSHARES 1664             // 1536 full + 128 shared-by-2 conv shares
#define STRIDE (NSHARES * NTHR)  // 425984 = 104*4096 -> residue-invariant
#define TOTAL_F4 (4096 * 4096)

typedef float f4 __attribute__((ext_vector_type(4)));

// R8-champion copy body (branchy, plain loads + NT stores), parameterized by
// (t0, step); step is a compile-time constant at each call site.
template <int STEP>
__device__ __forceinline__ void copy_range(int t0,
                                           const f4* __restrict__ c4,
                                           const f4* __restrict__ i4,
                                           f4* __restrict__ o4,
                                           int iw, int iwi, bool upd)
{
    if (!upd) {
        for (int i = t0; i < TOTAL_F4; i += STEP)
            __builtin_nontemporal_store(c4[i], o4 + i);
    } else if (iw != 0) {            // case A: plain copy + column override
        const int target = 3 * 1024 + iwi * 16;
        for (int i = t0; i < TOTAL_F4; i += STEP) {
            const int r = i & 4095;
            const f4* src = c4 + i;
            if ((r & ~15) == target)                       // h==3 && w==iwi
                src = i4 + ((i >> 12) << 4) + (r & 15);
            __builtin_nontemporal_store(*src, o4 + i);
        }
    } else if (iwi != 0) {           // case B: shift rows up, insert at (2,iwi), zero row 3
        for (int i = t0; i < TOTAL_F4; i += STEP) {
            const int r = i & 4095;
            const int h = r >> 10;
            f4 v = (f4)(0.f);
            if (h == 2 && ((r >> 4) & 63) == iwi) v = i4[((i >> 12) << 4) + (r & 15)];
            else if (h < 3) v = c4[i + 1024];
            __builtin_nontemporal_store(v, o4 + i);
        }
    } else {                         // case C: shift rows up, row 3 = inputs at col 0 else 0
        for (int i = t0; i < TOTAL_F4; i += STEP) {
            const int r = i & 4095;
            const int h = r >> 10;
            f4 v = (f4)(0.f);
            if (h == 3) { if (((r >> 4) & 63) == 0) v = i4[((i >> 12) << 4) + (r & 15)]; }
            else v = c4[i + 1024];
            __builtin_nontemporal_store(v, o4 + i);
        }
    }
}

// d_out layout: y[4096][64] followed by cache_new[4096][4][64][64]
__global__ __launch_bounds__(256)
void fmc_fused(const float* __restrict__ inputs,
               const float* __restrict__ cache,
               const float* __restrict__ wk,
               const float* __restrict__ bias,
               const int* __restrict__ idxp,
               float* __restrict__ y_out,
               float* __restrict__ cache_out)
{
    const int idx = idxp[0];
    int iw = idx % 64;        if (iw < 0)  iw += 64;
    int iwi = (idx - 1) % 64; if (iwi < 0) iwi += 64;
    const bool upd = (idx - 1) >= 0;   // EXCLUSIVE=True
    const int tid = threadIdx.x;

    const f4* __restrict__ c4 = (const f4*)cache;
    const f4* __restrict__ i4 = (const f4*)inputs;
    f4* __restrict__ o4 = (f4*)cache_out;

    if (blockIdx.x < NB_CONV) {
        // ---------------- conv part: y[b][fo] for 16 batch rows ----------------
        __shared__ float Ws[64][68];   // [ci][fo], padded -> conflict-free
        __shared__ float Xs[64][18];   // [ci][b],  padded -> conflict-free
        const int bbase = blockIdx.x * 16;
        const int fog = tid & 15;      // fo group: fo = 4*fog
        const int bp  = tid >> 4;      // compute threads: bp<8 -> b pair

        float acc[2][4];
        if (tid < 128) {
            const f4 bv = *(const f4*)(bias + (fog << 2));
            acc[0][0]=bv.x; acc[0][1]=bv.y; acc[0][2]=bv.z; acc[0][3]=bv.w;
            acc[1][0]=bv.x; acc[1][1]=bv.y; acc[1][2]=bv.z; acc[1][3]=bv.w;
        }

        for (int kh = 0; kh < 4; ++kh) {
            for (int kw = 0; kw < 7; ++kw) {
                if (kh == 3 && kw >= 3) break;          // autoregressive mask
                const int col = iw - 3 + kw;            // window col -> cache col
                int kind;                                // 0 zero, 1 inputs, 2 cache
                int hs = kh;
                if (col < 0 || col >= 64) kind = 0;
                else if (!upd) kind = 2;
                else if (iw != 0) kind = (kh == 3 && col == iwi) ? 1 : 2;   // case A
                else if (iwi != 0) {                                        // case B: shift(add)
                    if (kh == 3) kind = 0;
                    else if (kh == 2 && col == iwi) kind = 1;
                    else { kind = 2; hs = kh + 1; }
                } else {                                                     // case C: add(shift)
                    if (kh == 3) kind = (col == 0) ? 1 : 0;
                    else { kind = 2; hs = kh + 1; }
                }

                __syncthreads();   // protect LDS from previous tap's readers
                // stage W tap: [ci][fo] 64x64
                const float* wt = wk + (kh * 7 + kw) * 4096;
                #pragma unroll
                for (int i = 0; i < 4; ++i) {
                    const int f4i = tid + (i << 8);
                    const int ci = f4i >> 4;
                    const int fo = (f4i & 15) << 2;
                    *(f4*)&Ws[ci][fo] = *(const f4*)(wt + ci * 64 + fo);
                }
                // stage X (transposed): Xs[ci][b]
                {
                    const int bl = tid >> 4;
                    const int c4i = (tid & 15) << 2;
                    f4 v = (f4)(0.f);
                    if (kind == 1)
                        v = *(const f4*)(inputs + (bbase + bl) * 64 + c4i);
                    else if (kind == 2)
                        v = *(const f4*)(cache + ((((bbase + bl) << 2) + hs) * 64 + col) * 64 + c4i);
                    Xs[c4i + 0][bl] = v.x;
                    Xs[c4i + 1][bl] = v.y;
                    Xs[c4i + 2][bl] = v.z;
                    Xs[c4i + 3][bl] = v.w;
                }
                __syncthreads();

                if (tid < 128) {
                    #pragma unroll 16
                    for (int ci = 0; ci < 64; ++ci) {
                        const f4 w = *(const f4*)&Ws[ci][fog << 2];
                        const float2 x = *(const float2*)&Xs[ci][bp << 1];
                        acc[0][0] = fmaf(x.x, w.x, acc[0][0]);
                        acc[0][1] = fmaf(x.x, w.y, acc[0][1]);
                        acc[0][2] = fmaf(x.x, w.z, acc[0][2]);
                        acc[0][3] = fmaf(x.x, w.w, acc[0][3]);
                        acc[1][0] = fmaf(x.y, w.x, acc[1][0]);
                        acc[1][1] = fmaf(x.y, w.y, acc[1][1]);
                        acc[1][2] = fmaf(x.y, w.z, acc[1][2]);
                        acc[1][3] = fmaf(x.y, w.w, acc[1][3]);
                    }
                }
            }
        }
        if (tid < 128) {
            float* y0 = y_out + (bbase + (bp << 1)) * 64 + (fog << 2);
            *(f4*)y0        = (f4){acc[0][0], acc[0][1], acc[0][2], acc[0][3]};
            *(f4*)(y0 + 64) = (f4){acc[1][0], acc[1][1], acc[1][2], acc[1][3]};
        }

        // Conv blocks then take a HALF share each: blocks 2k and 2k+1 split
        // share (1536+k) by alternating iterations (step = 2*STRIDE).
        const int b = blockIdx.x;
        const int share = NB_COPYF + (b >> 1);
        const int t0 = share * NTHR + tid + ((b & 1) ? STRIDE : 0);
        copy_range<2 * STRIDE>(t0, c4, i4, o4, iw, iwi, upd);
    } else {
        // Dedicated copy blocks: one full share each (7.7% thicker than R8's).
        const int t0 = (blockIdx.x - NB_CONV) * NTHR + tid;
        copy_range<STRIDE>(t0, c4, i4, o4, iw, iwi, upd);
    }
}

extern "C" void kernel_launch(void* const* d_in, const int* in_sizes, int n_in,
                              void* d_out, int out_size, void* d_ws, size_t ws_size,
                              hipStream_t stream) {
    const float* inputs = (const float*)d_in[0];
    const float* cache  = (const float*)d_in[1];
    const float* wk     = (const float*)d_in[2];
    const float* bias   = (const float*)d_in[3];
    const int*   idxp   = (const int*)d_in[4];
    float* y_out = (float*)d_out;
    float* cache_out = (float*)d_out + 4096 * 64;
    fmc_fused<<<NB_TOTAL, NTHR, 0, stream>>>(inputs, cache, wk, bias, idxp,
                                             y_out, cache_out);
}